// Round 4
// baseline (163.026 us; speedup 1.0000x reference)
//
#include <hip/hip_runtime.h>

// NRI MLP decoder, round 4: fused, wave-per-receiver, f16 LDS staging.
// B=8, N=64, T=50 (49 used), D=4, H=64, K=2 (only relation i=1), E=4032.
// Grid = B*49*16 = 6272 blocks, 256 threads (4 waves); block = (b,t, 4
// receivers), wave = 1 receiver. V/P staged in LDS as f16 so the h-build is
// packed (v_pk_add_f16 + v_pk_max_f16) and A-frags need no repack.
// Node MLP: 3 MFMA layers on the block's 4 rows (garbage rows 4..15 are
// harmless: D row m depends only on A row m; only valid rows stored).

#define NB 8
#define NN 64
#define NT 50
#define NTO 49
#define ND 4
#define NE 4032

typedef _Float16 f16x8 __attribute__((ext_vector_type(8)));
typedef _Float16 f16x2 __attribute__((ext_vector_type(2)));
typedef float f32x4 __attribute__((ext_vector_type(4)));

union Frag8 { unsigned u[4]; f16x8 f; f16x2 h[4]; };

__device__ __forceinline__ unsigned pk16(float lo, float hi) {
  return __builtin_bit_cast(unsigned, __builtin_amdgcn_cvt_pkrtz(lo, hi));
}

#define MFMA16(A, B, C) __builtin_amdgcn_mfma_f32_16x16x32_f16((A), (B), (C), 0, 0, 0)

__global__ __launch_bounds__(256) void nri_fused_kernel(
    const float* __restrict__ inputs,   // (B,N,T,D)
    const float* __restrict__ rel_type, // (B,1,E,2)
    const float* __restrict__ fc1_w,    // (2,64,8)
    const float* __restrict__ fc1_b,    // (2,64)
    const float* __restrict__ fc2_w,    // (2,64,64)
    const float* __restrict__ fc2_b,    // (2,64)
    const float* __restrict__ out1_w,   // (64,68)
    const float* __restrict__ out1_b,   // (64)
    const float* __restrict__ out2_w,   // (64,64)
    const float* __restrict__ out2_b,   // (64)
    const float* __restrict__ out3_w,   // (4,64)
    const float* __restrict__ out3_b,   // (4)
    float* __restrict__ out)            // (B,N,49,4)
{
  __shared__ _Float16 Vh[NN * 72];    // V[s][k] f16, row stride 72
  __shared__ _Float16 Ph[4 * 72];     // U[n][k]+b1[k] f16, block's 4 receivers
  __shared__ float    Rl[4 * NN];     // rt[n][s]
  __shared__ float4   Xl[4];          // x rows of block receivers
  __shared__ float    AggL[16 * 68];  // agg rows 0..3 valid
  __shared__ float    H1L[16 * 68];
  __shared__ float    H2L[16 * 68];

  const int bid    = blockIdx.x;
  const int tilei  = bid & 15;
  const int t      = (bid >> 4) % NTO;
  const int b      = bid / (16 * NTO);
  const int n_base = tilei * 4;
  const int tid  = threadIdx.x;
  const int lane = tid & 63;
  const int w    = tid >> 6;
  const int q    = lane >> 4;
  const int r    = lane & 15;

  // ---------------- staging ----------------
  {
    const int k = lane;
    const float4 w1r = *(const float4*)(fc1_w + 512 + k * 8);
    const float4 w1s = *(const float4*)(fc1_w + 516 + k * 8);
    const float  b1k = fc1_b[64 + k];
    // V rows: wave w stages senders w*16 .. w*16+15
#pragma unroll 4
    for (int i = w * 16; i < w * 16 + 16; ++i) {
      const float4 x = *(const float4*)(inputs + ((b * NN + i) * NT + t) * ND);
      Vh[i * 72 + k] = (_Float16)(w1s.x*x.x + w1s.y*x.y + w1s.z*x.z + w1s.w*x.w);
    }
    // P row for this wave's receiver
    {
      const int n = n_base + w;
      const float4 x = *(const float4*)(inputs + ((b * NN + n) * NT + t) * ND);
      Ph[w * 72 + k] = (_Float16)(b1k + w1r.x*x.x + w1r.y*x.y + w1r.z*x.z + w1r.w*x.w);
    }
  }
  {
    const int i = w, s = lane;
    const int n = n_base + i;
    Rl[i * NN + s] = (s == n) ? 0.f
                   : rel_type[(b * NE + n * 63 + (s < n ? s : s - 1)) * 2 + 1];
  }
  if (tid < 4)
    Xl[tid] = *(const float4*)(inputs + ((b * NN + n_base + tid) * NT + t) * ND);

  // ---- W2 (relation 1) f16 B-frags, register-resident
  Frag8 bfr[4][2];
  float b2l[4];
#pragma unroll
  for (int nt = 0; nt < 4; ++nt) {
    const int o = nt * 16 + r;
    b2l[nt] = fc2_b[64 + o];
#pragma unroll
    for (int ks = 0; ks < 2; ++ks) {
      const float* p = fc2_w + 4096 + o * 64 + ks * 32 + q * 8;
      const float4 c0 = *(const float4*)p;
      const float4 c1 = *(const float4*)(p + 4);
      bfr[nt][ks].u[0] = pk16(c0.x, c0.y);
      bfr[nt][ks].u[1] = pk16(c0.z, c0.w);
      bfr[nt][ks].u[2] = pk16(c1.x, c1.y);
      bfr[nt][ks].u[3] = pk16(c1.z, c1.w);
    }
  }
  __syncthreads();

  // ---------------- edge phase: wave w = receiver n_base + w ----------------
  const int ni = w;
  Frag8 pa0, pa1;
  {
    const _Float16* pp = Ph + ni * 72 + q * 8;
    pa0.f = *(const f16x8*)pp;         // k = q*8 .. q*8+7
    pa1.f = *(const f16x8*)(pp + 32);  // k = 32 + q*8 ..
  }

  float ag0 = 0.f, ag1 = 0.f, ag2 = 0.f, ag3 = 0.f;
#pragma unroll
  for (int st = 0; st < 4; ++st) {
    const int s = st * 16 + r;
    const _Float16* vp = Vh + s * 72 + q * 8;
    Frag8 va0, va1, a0, a1;
    va0.f = *(const f16x8*)vp;
    va1.f = *(const f16x8*)(vp + 32);
    const f16x2 z = {(_Float16)0.f, (_Float16)0.f};
#pragma unroll
    for (int j = 0; j < 4; ++j) {
      a0.h[j] = __builtin_elementwise_max((f16x2)(pa0.h[j] + va0.h[j]), z);
      a1.h[j] = __builtin_elementwise_max((f16x2)(pa1.h[j] + va1.h[j]), z);
    }

    f32x4 d0 = {b2l[0], b2l[0], b2l[0], b2l[0]};
    f32x4 d1 = {b2l[1], b2l[1], b2l[1], b2l[1]};
    f32x4 d2 = {b2l[2], b2l[2], b2l[2], b2l[2]};
    f32x4 d3 = {b2l[3], b2l[3], b2l[3], b2l[3]};
    d0 = MFMA16(a0.f, bfr[0][0].f, d0); d0 = MFMA16(a1.f, bfr[0][1].f, d0);
    d1 = MFMA16(a0.f, bfr[1][0].f, d1); d1 = MFMA16(a1.f, bfr[1][1].f, d1);
    d2 = MFMA16(a0.f, bfr[2][0].f, d2); d2 = MFMA16(a1.f, bfr[2][1].f, d2);
    d3 = MFMA16(a0.f, bfr[3][0].f, d3); d3 = MFMA16(a1.f, bfr[3][1].f, d3);

    const float4 rt4 = *(const float4*)(Rl + ni * NN + st * 16 + q * 4);
    const float rte[4] = {rt4.x, rt4.y, rt4.z, rt4.w};
#pragma unroll
    for (int e = 0; e < 4; ++e) {
      ag0 = fmaf(rte[e], fmaxf(d0[e], 0.f), ag0);
      ag1 = fmaf(rte[e], fmaxf(d1[e], 0.f), ag1);
      ag2 = fmaf(rte[e], fmaxf(d2[e], 0.f), ag2);
      ag3 = fmaf(rte[e], fmaxf(d3[e], 0.f), ag3);
    }
  }
  // quads each summed 16 senders -> reduce, lane(q,r) keeps o = q*16+r = lane
  ag0 += __shfl_xor(ag0, 16); ag0 += __shfl_xor(ag0, 32);
  ag1 += __shfl_xor(ag1, 16); ag1 += __shfl_xor(ag1, 32);
  ag2 += __shfl_xor(ag2, 16); ag2 += __shfl_xor(ag2, 32);
  ag3 += __shfl_xor(ag3, 16); ag3 += __shfl_xor(ag3, 32);
  const float aval = (q == 0) ? ag0 : (q == 1) ? ag1 : (q == 2) ? ag2 : ag3;
  AggL[ni * 68 + lane] = aval;

  // ---- node weights (independent of agg; overlap the barrier drain)
  const int o = w * 16 + r;  // this wave's output column for layers 1 & 2
  Frag8 B1[2], B2[2];
#pragma unroll
  for (int ks = 0; ks < 2; ++ks) {
    const float* p1 = out1_w + o * 68 + 4 + ks * 32 + q * 8;
    const float4 c0 = *(const float4*)p1;
    const float4 c1 = *(const float4*)(p1 + 4);
    B1[ks].u[0] = pk16(c0.x, c0.y); B1[ks].u[1] = pk16(c0.z, c0.w);
    B1[ks].u[2] = pk16(c1.x, c1.y); B1[ks].u[3] = pk16(c1.z, c1.w);
    const float* p2 = out2_w + o * 64 + ks * 32 + q * 8;
    const float4 e0 = *(const float4*)p2;
    const float4 e1 = *(const float4*)(p2 + 4);
    B2[ks].u[0] = pk16(e0.x, e0.y); B2[ks].u[1] = pk16(e0.z, e0.w);
    B2[ks].u[2] = pk16(e1.x, e1.y); B2[ks].u[3] = pk16(e1.z, e1.w);
  }
  const float4 w1x = *(const float4*)(out1_w + o * 68);
  const float b1o = out1_b[o];
  const float b2o = out2_b[o];
  __syncthreads();

  // ---------------- node phase (rows = block's 4 receivers) ----------------
  // Layer 1: h1[n][o] = relu(b1 + x[n]·w1x + agg[n]·W1k[o])
  {
    Frag8 A0, A1;
    const float* gp = AggL + r * 68 + q * 8;
    const float4 g0 = *(const float4*)gp;
    const float4 g1 = *(const float4*)(gp + 4);
    const float4 g2 = *(const float4*)(gp + 32);
    const float4 g3 = *(const float4*)(gp + 36);
    A0.u[0] = pk16(g0.x, g0.y); A0.u[1] = pk16(g0.z, g0.w);
    A0.u[2] = pk16(g1.x, g1.y); A0.u[3] = pk16(g1.z, g1.w);
    A1.u[0] = pk16(g2.x, g2.y); A1.u[1] = pk16(g2.z, g2.w);
    A1.u[2] = pk16(g3.x, g3.y); A1.u[3] = pk16(g3.z, g3.w);
    f32x4 d = {b1o, b1o, b1o, b1o};
    d = MFMA16(A0.f, B1[0].f, d);
    d = MFMA16(A1.f, B1[1].f, d);
    if (q == 0) {  // valid rows n = 0..3
#pragma unroll
      for (int reg = 0; reg < 4; ++reg) {
        const float4 x = Xl[reg];
        const float hv = d[reg] + x.x*w1x.x + x.y*w1x.y + x.z*w1x.z + x.w*w1x.w;
        H1L[reg * 68 + o] = fmaxf(hv, 0.f);
      }
    }
  }
  __syncthreads();

  // Layer 2: h2 = relu(b2 + h1·W2o^T)
  {
    Frag8 A0, A1;
    const float* gp = H1L + r * 68 + q * 8;
    const float4 g0 = *(const float4*)gp;
    const float4 g1 = *(const float4*)(gp + 4);
    const float4 g2 = *(const float4*)(gp + 32);
    const float4 g3 = *(const float4*)(gp + 36);
    A0.u[0] = pk16(g0.x, g0.y); A0.u[1] = pk16(g0.z, g0.w);
    A0.u[2] = pk16(g1.x, g1.y); A0.u[3] = pk16(g1.z, g1.w);
    A1.u[0] = pk16(g2.x, g2.y); A1.u[1] = pk16(g2.z, g2.w);
    A1.u[2] = pk16(g3.x, g3.y); A1.u[3] = pk16(g3.z, g3.w);
    f32x4 d = {b2o, b2o, b2o, b2o};
    d = MFMA16(A0.f, B2[0].f, d);
    d = MFMA16(A1.f, B2[1].f, d);
    if (q == 0) {
#pragma unroll
      for (int reg = 0; reg < 4; ++reg)
        H2L[reg * 68 + o] = fmaxf(d[reg], 0.f);
    }
  }
  __syncthreads();

  // Layer 3 (wave 0): delta[n][dm] = b3[dm] + h2[n]·W3[dm]; out = x + delta
  if (w == 0) {
    Frag8 B3[2];
#pragma unroll
    for (int ks = 0; ks < 2; ++ks) {
      const float* p3 = out3_w + (r & 3) * 64 + ks * 32 + q * 8;
      const float4 c0 = *(const float4*)p3;
      const float4 c1 = *(const float4*)(p3 + 4);
      B3[ks].u[0] = pk16(c0.x, c0.y); B3[ks].u[1] = pk16(c0.z, c0.w);
      B3[ks].u[2] = pk16(c1.x, c1.y); B3[ks].u[3] = pk16(c1.z, c1.w);
    }
    Frag8 A0, A1;
    const float* gp = H2L + r * 68 + q * 8;
    const float4 g0 = *(const float4*)gp;
    const float4 g1 = *(const float4*)(gp + 4);
    const float4 g2 = *(const float4*)(gp + 32);
    const float4 g3 = *(const float4*)(gp + 36);
    A0.u[0] = pk16(g0.x, g0.y); A0.u[1] = pk16(g0.z, g0.w);
    A0.u[2] = pk16(g1.x, g1.y); A0.u[3] = pk16(g1.z, g1.w);
    A1.u[0] = pk16(g2.x, g2.y); A1.u[1] = pk16(g2.z, g2.w);
    A1.u[2] = pk16(g3.x, g3.y); A1.u[3] = pk16(g3.z, g3.w);
    const float b3o = out3_b[r & 3];
    f32x4 d = {b3o, b3o, b3o, b3o};
    d = MFMA16(A0.f, B3[0].f, d);
    d = MFMA16(A1.f, B3[1].f, d);
    // D[row=q*4+reg][col=r]: valid rows 0..3 (q==0), valid cols r<4
    if (q == 0 && r < 4) {
      const float* xf = (const float*)Xl;
#pragma unroll
      for (int reg = 0; reg < 4; ++reg) {
        out[((b * NN + n_base + reg) * NTO + t) * ND + r] = xf[reg * 4 + r] + d[reg];
      }
    }
  }
}

extern "C" void kernel_launch(void* const* d_in, const int* in_sizes, int n_in,
                              void* d_out, int out_size, void* d_ws, size_t ws_size,
                              hipStream_t stream) {
  const float* inputs   = (const float*)d_in[0];
  const float* rel_type = (const float*)d_in[1];
  const float* fc1_w  = (const float*)d_in[4];
  const float* fc1_b  = (const float*)d_in[5];
  const float* fc2_w  = (const float*)d_in[6];
  const float* fc2_b  = (const float*)d_in[7];
  const float* out1_w = (const float*)d_in[8];
  const float* out1_b = (const float*)d_in[9];
  const float* out2_w = (const float*)d_in[10];
  const float* out2_b = (const float*)d_in[11];
  const float* out3_w = (const float*)d_in[12];
  const float* out3_b = (const float*)d_in[13];
  float* out = (float*)d_out;

  nri_fused_kernel<<<NB * NTO * 16, 256, 0, stream>>>(
      inputs, rel_type, fc1_w, fc1_b, fc2_w, fc2_b,
      out1_w, out1_b, out2_w, out2_b, out3_w, out3_b, out);
}

// Round 5
// 114.552 us; speedup vs baseline: 1.4232x; 1.4232x over previous
//
#include <hip/hip_runtime.h>

// NRI MLP decoder, round 5: round-3 block shape + f16 LDS staging (stride 68)
// + software-pipelined st loop + packed-f32 epilogue.
// B=8, N=64, T=50 (49 used), D=4, H=64, K=2 (only relation i=1), E=4032.
// Grid = B*49*4 = 1568 blocks, 256 threads (4 waves); block = (b,t,16
// receivers); wave = 4 receivers (serial np loop). Edge fc2 GEMM on
// mfma_f32_16x16x32_f16; node MLP = 3 more MFMA layers on the 16 rows.

#define NB 8
#define NN 64
#define NT 50
#define NTO 49
#define ND 4
#define NE 4032

typedef _Float16 f16x8 __attribute__((ext_vector_type(8)));
typedef _Float16 f16x2 __attribute__((ext_vector_type(2)));
typedef float f32x4 __attribute__((ext_vector_type(4)));
typedef float f32x2 __attribute__((ext_vector_type(2)));

union Frag8 { unsigned u[4]; f16x8 f; f16x2 h[4]; };

__device__ __forceinline__ unsigned pk16(float lo, float hi) {
  return __builtin_bit_cast(unsigned, __builtin_amdgcn_cvt_pkrtz(lo, hi));
}

#define MFMA16(A, B, C) __builtin_amdgcn_mfma_f32_16x16x32_f16((A), (B), (C), 0, 0, 0)

__global__ __launch_bounds__(256) void nri_fused_kernel(
    const float* __restrict__ inputs,   // (B,N,T,D)
    const float* __restrict__ rel_type, // (B,1,E,2)
    const float* __restrict__ fc1_w,    // (2,64,8)
    const float* __restrict__ fc1_b,    // (2,64)
    const float* __restrict__ fc2_w,    // (2,64,64)
    const float* __restrict__ fc2_b,    // (2,64)
    const float* __restrict__ out1_w,   // (64,68)
    const float* __restrict__ out1_b,   // (64)
    const float* __restrict__ out2_w,   // (64,64)
    const float* __restrict__ out2_b,   // (64)
    const float* __restrict__ out3_w,   // (4,64)
    const float* __restrict__ out3_b,   // (4)
    float* __restrict__ out)            // (B,N,49,4)
{
  __shared__ _Float16 Vh[NN * 68];    // V[s][k] f16; 34-dword rows -> <=2-way banks
  __shared__ _Float16 Ph[16 * 68];    // U[n][k]+b1[k] f16
  __shared__ float    Rl[16 * NN];    // rt[n][s]
  __shared__ float4   Xl[16];         // x rows of block receivers
  __shared__ float    AggL[16 * 68];  // agg[n][o]
  __shared__ float    H1L[16 * 68];
  __shared__ float    H2L[16 * 68];

  const int bid    = blockIdx.x;
  const int tile   = bid & 3;
  const int t      = (bid >> 2) % NTO;
  const int b      = bid / (4 * NTO);
  const int n_base = tile * 16;
  const int tid  = threadIdx.x;
  const int lane = tid & 63;
  const int w    = tid >> 6;
  const int q    = lane >> 4;
  const int r    = lane & 15;

  // ---------------- staging ----------------
  {
    const int k = lane;
    const float4 w1r = *(const float4*)(fc1_w + 512 + k * 8);
    const float4 w1s = *(const float4*)(fc1_w + 516 + k * 8);
    const float  b1k = fc1_b[64 + k];
#pragma unroll
    for (int ii = 0; ii < 16; ++ii) {            // V rows i = w, w+4, ...
      const int i = ii * 4 + w;
      const float4 x = *(const float4*)(inputs + ((b * NN + i) * NT + t) * ND);
      Vh[i * 68 + k] = (_Float16)(w1s.x*x.x + w1s.y*x.y + w1s.z*x.z + w1s.w*x.w);
    }
#pragma unroll
    for (int ii = 0; ii < 4; ++ii) {             // P rows
      const int i = ii * 4 + w;
      const float4 x = *(const float4*)(inputs + ((b * NN + n_base + i) * NT + t) * ND);
      Ph[i * 68 + k] = (_Float16)(b1k + w1r.x*x.x + w1r.y*x.y + w1r.z*x.z + w1r.w*x.w);
    }
  }
#pragma unroll
  for (int ii = 0; ii < 4; ++ii) {               // rt: 1024 entries
    const int idx = ii * 256 + tid;
    const int i = idx >> 6, s = idx & 63;
    const int n = n_base + i;
    Rl[idx] = (s == n) ? 0.f
                       : rel_type[(b * NE + n * 63 + (s < n ? s : s - 1)) * 2 + 1];
  }
  if (tid < 16)
    Xl[tid] = *(const float4*)(inputs + ((b * NN + n_base + tid) * NT + t) * ND);

  // ---- W2 (relation 1) f16 B-frags, register-resident
  Frag8 bfr[4][2];
  float b2l[4];
#pragma unroll
  for (int nt = 0; nt < 4; ++nt) {
    const int o = nt * 16 + r;
    b2l[nt] = fc2_b[64 + o];
#pragma unroll
    for (int ks = 0; ks < 2; ++ks) {
      const float* p = fc2_w + 4096 + o * 64 + ks * 32 + q * 8;
      const float4 c0 = *(const float4*)p;
      const float4 c1 = *(const float4*)(p + 4);
      bfr[nt][ks].u[0] = pk16(c0.x, c0.y);
      bfr[nt][ks].u[1] = pk16(c0.z, c0.w);
      bfr[nt][ks].u[2] = pk16(c1.x, c1.y);
      bfr[nt][ks].u[3] = pk16(c1.z, c1.w);
    }
  }
  __syncthreads();

  // ---------------- edge phase: wave w, 4 serial receivers ----------------
#pragma unroll 1
  for (int np = 0; np < 4; ++np) {
    const int ni = w * 4 + np;
    Frag8 pa0, pa1;
    pa0.f = *(const f16x8*)(Ph + ni * 68 + q * 8);        // k = q*8..q*8+7
    pa1.f = *(const f16x8*)(Ph + ni * 68 + 32 + q * 8);   // k = 32+q*8..

    float4 rt4[4];
#pragma unroll
    for (int st = 0; st < 4; ++st)
      rt4[st] = *(const float4*)(Rl + ni * NN + st * 16 + q * 4);

    // preload st=0 V frags
    Frag8 va0, va1;
    {
      const _Float16* vp = Vh + r * 68 + q * 8;
      va0.f = *(const f16x8*)vp;
      va1.f = *(const f16x8*)(vp + 32);
    }

    f32x2 ag0 = {0.f, 0.f}, ag1 = {0.f, 0.f}, ag2 = {0.f, 0.f}, ag3 = {0.f, 0.f};
#pragma unroll
    for (int st = 0; st < 4; ++st) {
      // prefetch next st's V frags (overlaps this iteration's compute)
      Frag8 nva0, nva1;
      if (st < 3) {
        const _Float16* vp = Vh + ((st + 1) * 16 + r) * 68 + q * 8;
        nva0.f = *(const f16x8*)vp;
        nva1.f = *(const f16x8*)(vp + 32);
      }

      // h = relu(P + V), packed f16
      Frag8 a0, a1;
      const f16x2 z = {(_Float16)0.f, (_Float16)0.f};
#pragma unroll
      for (int j = 0; j < 4; ++j) {
        a0.h[j] = __builtin_elementwise_max((f16x2)(pa0.h[j] + va0.h[j]), z);
        a1.h[j] = __builtin_elementwise_max((f16x2)(pa1.h[j] + va1.h[j]), z);
      }

      f32x4 d0 = {b2l[0], b2l[0], b2l[0], b2l[0]};
      f32x4 d1 = {b2l[1], b2l[1], b2l[1], b2l[1]};
      f32x4 d2 = {b2l[2], b2l[2], b2l[2], b2l[2]};
      f32x4 d3 = {b2l[3], b2l[3], b2l[3], b2l[3]};
      d0 = MFMA16(a0.f, bfr[0][0].f, d0); d0 = MFMA16(a1.f, bfr[0][1].f, d0);
      d1 = MFMA16(a0.f, bfr[1][0].f, d1); d1 = MFMA16(a1.f, bfr[1][1].f, d1);
      d2 = MFMA16(a0.f, bfr[2][0].f, d2); d2 = MFMA16(a1.f, bfr[2][1].f, d2);
      d3 = MFMA16(a0.f, bfr[3][0].f, d3); d3 = MFMA16(a1.f, bfr[3][1].f, d3);

      // epilogue: ag += rt * relu(d), as f32x2 pairs (v_pk_fma_f32-friendly)
      const f32x2 zz = {0.f, 0.f};
      const f32x2 rtA = {rt4[st].x, rt4[st].y};
      const f32x2 rtB = {rt4[st].z, rt4[st].w};
      f32x2 p0, p1;
      p0 = __builtin_elementwise_max((f32x2){d0[0], d0[1]}, zz);
      p1 = __builtin_elementwise_max((f32x2){d0[2], d0[3]}, zz);
      ag0 += rtA * p0 + rtB * p1;
      p0 = __builtin_elementwise_max((f32x2){d1[0], d1[1]}, zz);
      p1 = __builtin_elementwise_max((f32x2){d1[2], d1[3]}, zz);
      ag1 += rtA * p0 + rtB * p1;
      p0 = __builtin_elementwise_max((f32x2){d2[0], d2[1]}, zz);
      p1 = __builtin_elementwise_max((f32x2){d2[2], d2[3]}, zz);
      ag2 += rtA * p0 + rtB * p1;
      p0 = __builtin_elementwise_max((f32x2){d3[0], d3[1]}, zz);
      p1 = __builtin_elementwise_max((f32x2){d3[2], d3[3]}, zz);
      ag3 += rtA * p0 + rtB * p1;

      va0 = nva0; va1 = nva1;
    }
    float s0 = ag0.x + ag0.y, s1 = ag1.x + ag1.y;
    float s2 = ag2.x + ag2.y, s3 = ag3.x + ag3.y;
    // quads each summed 16 senders -> reduce; lane keeps o = q*16+r = lane
    s0 += __shfl_xor(s0, 16); s0 += __shfl_xor(s0, 32);
    s1 += __shfl_xor(s1, 16); s1 += __shfl_xor(s1, 32);
    s2 += __shfl_xor(s2, 16); s2 += __shfl_xor(s2, 32);
    s3 += __shfl_xor(s3, 16); s3 += __shfl_xor(s3, 32);
    const float aval = (q == 0) ? s0 : (q == 1) ? s1 : (q == 2) ? s2 : s3;
    AggL[ni * 68 + lane] = aval;
  }

  // ---- node weights (independent of agg; overlap barrier drain)
  const int o = w * 16 + r;  // this wave's output column, layers 1 & 2
  Frag8 B1[2], B2[2];
#pragma unroll
  for (int ks = 0; ks < 2; ++ks) {
    const float* p1 = out1_w + o * 68 + 4 + ks * 32 + q * 8;
    const float4 c0 = *(const float4*)p1;
    const float4 c1 = *(const float4*)(p1 + 4);
    B1[ks].u[0] = pk16(c0.x, c0.y); B1[ks].u[1] = pk16(c0.z, c0.w);
    B1[ks].u[2] = pk16(c1.x, c1.y); B1[ks].u[3] = pk16(c1.z, c1.w);
    const float* p2 = out2_w + o * 64 + ks * 32 + q * 8;
    const float4 e0 = *(const float4*)p2;
    const float4 e1 = *(const float4*)(p2 + 4);
    B2[ks].u[0] = pk16(e0.x, e0.y); B2[ks].u[1] = pk16(e0.z, e0.w);
    B2[ks].u[2] = pk16(e1.x, e1.y); B2[ks].u[3] = pk16(e1.z, e1.w);
  }
  const float4 w1x = *(const float4*)(out1_w + o * 68);
  const float b1o = out1_b[o];
  const float b2o = out2_b[o];
  __syncthreads();

  // ---------------- node phase (16 rows) ----------------
  // Layer 1: h1[n][o] = relu(b1 + x[n]·w1x + agg[n]·W1k[o])
  {
    Frag8 A0, A1;
    const float* gp = AggL + r * 68 + q * 8;
    const float4 g0 = *(const float4*)gp;
    const float4 g1 = *(const float4*)(gp + 4);
    const float4 g2 = *(const float4*)(gp + 32);
    const float4 g3 = *(const float4*)(gp + 36);
    A0.u[0] = pk16(g0.x, g0.y); A0.u[1] = pk16(g0.z, g0.w);
    A0.u[2] = pk16(g1.x, g1.y); A0.u[3] = pk16(g1.z, g1.w);
    A1.u[0] = pk16(g2.x, g2.y); A1.u[1] = pk16(g2.z, g2.w);
    A1.u[2] = pk16(g3.x, g3.y); A1.u[3] = pk16(g3.z, g3.w);
    f32x4 d = {b1o, b1o, b1o, b1o};
    d = MFMA16(A0.f, B1[0].f, d);
    d = MFMA16(A1.f, B1[1].f, d);
#pragma unroll
    for (int reg = 0; reg < 4; ++reg) {
      const int n = q * 4 + reg;
      const float4 x = Xl[n];
      const float hv = d[reg] + x.x*w1x.x + x.y*w1x.y + x.z*w1x.z + x.w*w1x.w;
      H1L[n * 68 + o] = fmaxf(hv, 0.f);
    }
  }
  __syncthreads();

  // Layer 2: h2 = relu(b2 + h1·W2o^T)
  {
    Frag8 A0, A1;
    const float* gp = H1L + r * 68 + q * 8;
    const float4 g0 = *(const float4*)gp;
    const float4 g1 = *(const float4*)(gp + 4);
    const float4 g2 = *(const float4*)(gp + 32);
    const float4 g3 = *(const float4*)(gp + 36);
    A0.u[0] = pk16(g0.x, g0.y); A0.u[1] = pk16(g0.z, g0.w);
    A0.u[2] = pk16(g1.x, g1.y); A0.u[3] = pk16(g1.z, g1.w);
    A1.u[0] = pk16(g2.x, g2.y); A1.u[1] = pk16(g2.z, g2.w);
    A1.u[2] = pk16(g3.x, g3.y); A1.u[3] = pk16(g3.z, g3.w);
    f32x4 d = {b2o, b2o, b2o, b2o};
    d = MFMA16(A0.f, B2[0].f, d);
    d = MFMA16(A1.f, B2[1].f, d);
#pragma unroll
    for (int reg = 0; reg < 4; ++reg) {
      const int n = q * 4 + reg;
      H2L[n * 68 + o] = fmaxf(d[reg], 0.f);
    }
  }
  __syncthreads();

  // Layer 3 (wave 0): delta[n][dm] = b3[dm] + h2[n]·W3[dm]; out = x + delta
  if (w == 0) {
    Frag8 B3[2];
#pragma unroll
    for (int ks = 0; ks < 2; ++ks) {
      const float* p3 = out3_w + (r & 3) * 64 + ks * 32 + q * 8;
      const float4 c0 = *(const float4*)p3;
      const float4 c1 = *(const float4*)(p3 + 4);
      B3[ks].u[0] = pk16(c0.x, c0.y); B3[ks].u[1] = pk16(c0.z, c0.w);
      B3[ks].u[2] = pk16(c1.x, c1.y); B3[ks].u[3] = pk16(c1.z, c1.w);
    }
    Frag8 A0, A1;
    const float* gp = H2L + r * 68 + q * 8;
    const float4 g0 = *(const float4*)gp;
    const float4 g1 = *(const float4*)(gp + 4);
    const float4 g2 = *(const float4*)(gp + 32);
    const float4 g3 = *(const float4*)(gp + 36);
    A0.u[0] = pk16(g0.x, g0.y); A0.u[1] = pk16(g0.z, g0.w);
    A0.u[2] = pk16(g1.x, g1.y); A0.u[3] = pk16(g1.z, g1.w);
    A1.u[0] = pk16(g2.x, g2.y); A1.u[1] = pk16(g2.z, g2.w);
    A1.u[2] = pk16(g3.x, g3.y); A1.u[3] = pk16(g3.z, g3.w);
    const float b3o = out3_b[r & 3];
    f32x4 d = {b3o, b3o, b3o, b3o};
    d = MFMA16(A0.f, B3[0].f, d);
    d = MFMA16(A1.f, B3[1].f, d);
    if (r < 4) {  // valid cols; rows q*4+reg all valid
      const float* xf = (const float*)Xl;
#pragma unroll
      for (int reg = 0; reg < 4; ++reg) {
        const int n = q * 4 + reg;
        out[((b * NN + n_base + n) * NTO + t) * ND + r] = xf[n * 4 + r] + d[reg];
      }
    }
  }
}

extern "C" void kernel_launch(void* const* d_in, const int* in_sizes, int n_in,
                              void* d_out, int out_size, void* d_ws, size_t ws_size,
                              hipStream_t stream) {
  const float* inputs   = (const float*)d_in[0];
  const float* rel_type = (const float*)d_in[1];
  const float* fc1_w  = (const float*)d_in[4];
  const float* fc1_b  = (const float*)d_in[5];
  const float* fc2_w  = (const float*)d_in[6];
  const float* fc2_b  = (const float*)d_in[7];
  const float* out1_w = (const float*)d_in[8];
  const float* out1_b = (const float*)d_in[9];
  const float* out2_w = (const float*)d_in[10];
  const float* out2_b = (const float*)d_in[11];
  const float* out3_w = (const float*)d_in[12];
  const float* out3_b = (const float*)d_in[13];
  float* out = (float*)d_out;

  nri_fused_kernel<<<NB * NTO * 4, 256, 0, stream>>>(
      inputs, rel_type, fc1_w, fc1_b, fc2_w, fc2_b,
      out1_w, out1_b, out2_w, out2_b, out3_w, out3_b, out);
}

// Round 6
// 113.769 us; speedup vs baseline: 1.4330x; 1.0069x over previous
//
#include <hip/hip_runtime.h>

// NRI MLP decoder, round 6: round-5 structure + LDS shrink to <16 KB
// (f16 node tensors, H1/H2 aliased onto the edge-only V region, f16 rt)
// to test the 64KB-occupancy-pool hypothesis (2 -> 4 blocks/CU).
// B=8, N=64, T=50 (49 used), D=4, H=64, K=2 (only relation i=1), E=4032.
// Grid = B*49*4 = 1568 blocks, 256 threads (4 waves); block = (b,t,16
// receivers); wave = 4 receivers serial. Edge fc2 GEMM + 3 node layers on
// mfma_f32_16x16x32_f16; fp32 accumulate everywhere.

#define NB 8
#define NN 64
#define NT 50
#define NTO 49
#define ND 4
#define NE 4032

typedef _Float16 f16x8 __attribute__((ext_vector_type(8)));
typedef _Float16 f16x4 __attribute__((ext_vector_type(4)));
typedef _Float16 f16x2 __attribute__((ext_vector_type(2)));
typedef float f32x4 __attribute__((ext_vector_type(4)));
typedef float f32x2 __attribute__((ext_vector_type(2)));

union Frag8 { unsigned u[4]; f16x8 f; f16x2 h[4]; };

__device__ __forceinline__ unsigned pk16(float lo, float hi) {
  return __builtin_bit_cast(unsigned, __builtin_amdgcn_cvt_pkrtz(lo, hi));
}

#define MFMA16(A, B, C) __builtin_amdgcn_mfma_f32_16x16x32_f16((A), (B), (C), 0, 0, 0)

__global__ __launch_bounds__(256) void nri_fused_kernel(
    const float* __restrict__ inputs,   // (B,N,T,D)
    const float* __restrict__ rel_type, // (B,1,E,2)
    const float* __restrict__ fc1_w,    // (2,64,8)
    const float* __restrict__ fc1_b,    // (2,64)
    const float* __restrict__ fc2_w,    // (2,64,64)
    const float* __restrict__ fc2_b,    // (2,64)
    const float* __restrict__ out1_w,   // (64,68)
    const float* __restrict__ out1_b,   // (64)
    const float* __restrict__ out2_w,   // (64,64)
    const float* __restrict__ out2_b,   // (64)
    const float* __restrict__ out3_w,   // (4,64)
    const float* __restrict__ out3_b,   // (4)
    float* __restrict__ out)            // (B,N,49,4)
{
  // Manual LDS layout, 15872 B total (all sub-arrays 16B-aligned):
  //   [    0,  9216) Vh   f16[64*72]  V[s][k]          (edge only)
  //   [    0,  2304) H1L  f16[16*72]  alias, post-edge
  //   [ 4608,  6912) H2L  f16[16*72]  alias, post-edge
  //   [ 9216, 11264) Ph   f16[16*64]  U[n][k]+b1[k]
  //   [11264, 13312) Rl   f16[16*64]  rt[n][s]
  //   [13312, 13568) Xl   float4[16]
  //   [13568, 15872) AggL f16[16*72]
  __shared__ __align__(16) char smem[15872];
  _Float16* const Vh   = (_Float16*)(smem);
  _Float16* const H1L  = (_Float16*)(smem);
  _Float16* const H2L  = (_Float16*)(smem + 4608);
  _Float16* const Ph   = (_Float16*)(smem + 9216);
  _Float16* const Rl   = (_Float16*)(smem + 11264);
  float4*   const Xl   = (float4*)  (smem + 13312);
  _Float16* const AggL = (_Float16*)(smem + 13568);

  const int bid    = blockIdx.x;
  const int tile   = bid & 3;
  const int t      = (bid >> 2) % NTO;
  const int b      = bid / (4 * NTO);
  const int n_base = tile * 16;
  const int tid  = threadIdx.x;
  const int lane = tid & 63;
  const int w    = tid >> 6;
  const int q    = lane >> 4;
  const int r    = lane & 15;

  // ---------------- staging ----------------
  {
    const int k = lane;
    const float4 w1r = *(const float4*)(fc1_w + 512 + k * 8);
    const float4 w1s = *(const float4*)(fc1_w + 516 + k * 8);
    const float  b1k = fc1_b[64 + k];
#pragma unroll
    for (int ii = 0; ii < 16; ++ii) {            // V rows i = w, w+4, ...
      const int i = ii * 4 + w;
      const float4 x = *(const float4*)(inputs + ((b * NN + i) * NT + t) * ND);
      Vh[i * 72 + k] = (_Float16)(w1s.x*x.x + w1s.y*x.y + w1s.z*x.z + w1s.w*x.w);
    }
#pragma unroll
    for (int ii = 0; ii < 4; ++ii) {             // P rows (stride 64)
      const int i = ii * 4 + w;
      const float4 x = *(const float4*)(inputs + ((b * NN + n_base + i) * NT + t) * ND);
      Ph[i * 64 + k] = (_Float16)(b1k + w1r.x*x.x + w1r.y*x.y + w1r.z*x.z + w1r.w*x.w);
    }
  }
#pragma unroll
  for (int ii = 0; ii < 4; ++ii) {               // rt: 1024 entries, f16
    const int idx = ii * 256 + tid;
    const int i = idx >> 6, s = idx & 63;
    const int n = n_base + i;
    const float v = (s == n) ? 0.f
                  : rel_type[(b * NE + n * 63 + (s < n ? s : s - 1)) * 2 + 1];
    Rl[idx] = (_Float16)v;
  }
  if (tid < 16)
    Xl[tid] = *(const float4*)(inputs + ((b * NN + n_base + tid) * NT + t) * ND);

  // ---- W2 (relation 1) f16 B-frags, register-resident
  Frag8 bfr[4][2];
  float b2l[4];
#pragma unroll
  for (int nt = 0; nt < 4; ++nt) {
    const int o = nt * 16 + r;
    b2l[nt] = fc2_b[64 + o];
#pragma unroll
    for (int ks = 0; ks < 2; ++ks) {
      const float* p = fc2_w + 4096 + o * 64 + ks * 32 + q * 8;
      const float4 c0 = *(const float4*)p;
      const float4 c1 = *(const float4*)(p + 4);
      bfr[nt][ks].u[0] = pk16(c0.x, c0.y);
      bfr[nt][ks].u[1] = pk16(c0.z, c0.w);
      bfr[nt][ks].u[2] = pk16(c1.x, c1.y);
      bfr[nt][ks].u[3] = pk16(c1.z, c1.w);
    }
  }
  __syncthreads();

  // ---------------- edge phase: wave w, 4 serial receivers ----------------
#pragma unroll 1
  for (int np = 0; np < 4; ++np) {
    const int ni = w * 4 + np;
    Frag8 pa0, pa1;
    pa0.f = *(const f16x8*)(Ph + ni * 64 + q * 8);        // k = q*8..
    pa1.f = *(const f16x8*)(Ph + ni * 64 + 32 + q * 8);   // k = 32+q*8..

    // rt for this receiver: 16 f16 -> f32 regs
    float rtf[16];
#pragma unroll
    for (int st2 = 0; st2 < 4; ++st2) {
      const f16x4 rv = *(const f16x4*)(Rl + ni * 64 + st2 * 16 + q * 4);
      rtf[st2*4+0] = (float)rv[0]; rtf[st2*4+1] = (float)rv[1];
      rtf[st2*4+2] = (float)rv[2]; rtf[st2*4+3] = (float)rv[3];
    }

    // preload st=0 V frags
    Frag8 va0, va1;
    {
      const _Float16* vp = Vh + r * 72 + q * 8;
      va0.f = *(const f16x8*)vp;
      va1.f = *(const f16x8*)(vp + 32);
    }

    f32x2 ag0 = {0.f,0.f}, ag1 = {0.f,0.f}, ag2 = {0.f,0.f}, ag3 = {0.f,0.f};
#pragma unroll
    for (int st = 0; st < 4; ++st) {
      Frag8 nva0, nva1;
      if (st < 3) {  // prefetch next st's V frags
        const _Float16* vp = Vh + ((st + 1) * 16 + r) * 72 + q * 8;
        nva0.f = *(const f16x8*)vp;
        nva1.f = *(const f16x8*)(vp + 32);
      }

      // h = relu(P + V), packed f16
      Frag8 a0, a1;
      const f16x2 z = {(_Float16)0.f, (_Float16)0.f};
#pragma unroll
      for (int j = 0; j < 4; ++j) {
        a0.h[j] = __builtin_elementwise_max((f16x2)(pa0.h[j] + va0.h[j]), z);
        a1.h[j] = __builtin_elementwise_max((f16x2)(pa1.h[j] + va1.h[j]), z);
      }

      f32x4 d0 = {b2l[0], b2l[0], b2l[0], b2l[0]};
      f32x4 d1 = {b2l[1], b2l[1], b2l[1], b2l[1]};
      f32x4 d2 = {b2l[2], b2l[2], b2l[2], b2l[2]};
      f32x4 d3 = {b2l[3], b2l[3], b2l[3], b2l[3]};
      d0 = MFMA16(a0.f, bfr[0][0].f, d0); d0 = MFMA16(a1.f, bfr[0][1].f, d0);
      d1 = MFMA16(a0.f, bfr[1][0].f, d1); d1 = MFMA16(a1.f, bfr[1][1].f, d1);
      d2 = MFMA16(a0.f, bfr[2][0].f, d2); d2 = MFMA16(a1.f, bfr[2][1].f, d2);
      d3 = MFMA16(a0.f, bfr[3][0].f, d3); d3 = MFMA16(a1.f, bfr[3][1].f, d3);

      const f32x2 zz = {0.f, 0.f};
      const f32x2 rtA = {rtf[st*4+0], rtf[st*4+1]};
      const f32x2 rtB = {rtf[st*4+2], rtf[st*4+3]};
      f32x2 p0, p1;
      p0 = __builtin_elementwise_max((f32x2){d0[0], d0[1]}, zz);
      p1 = __builtin_elementwise_max((f32x2){d0[2], d0[3]}, zz);
      ag0 += rtA * p0 + rtB * p1;
      p0 = __builtin_elementwise_max((f32x2){d1[0], d1[1]}, zz);
      p1 = __builtin_elementwise_max((f32x2){d1[2], d1[3]}, zz);
      ag1 += rtA * p0 + rtB * p1;
      p0 = __builtin_elementwise_max((f32x2){d2[0], d2[1]}, zz);
      p1 = __builtin_elementwise_max((f32x2){d2[2], d2[3]}, zz);
      ag2 += rtA * p0 + rtB * p1;
      p0 = __builtin_elementwise_max((f32x2){d3[0], d3[1]}, zz);
      p1 = __builtin_elementwise_max((f32x2){d3[2], d3[3]}, zz);
      ag3 += rtA * p0 + rtB * p1;

      va0 = nva0; va1 = nva1;
    }
    float s0 = ag0.x + ag0.y, s1 = ag1.x + ag1.y;
    float s2 = ag2.x + ag2.y, s3 = ag3.x + ag3.y;
    s0 += __shfl_xor(s0, 16); s0 += __shfl_xor(s0, 32);
    s1 += __shfl_xor(s1, 16); s1 += __shfl_xor(s1, 32);
    s2 += __shfl_xor(s2, 16); s2 += __shfl_xor(s2, 32);
    s3 += __shfl_xor(s3, 16); s3 += __shfl_xor(s3, 32);
    const float aval = (q == 0) ? s0 : (q == 1) ? s1 : (q == 2) ? s2 : s3;
    AggL[ni * 72 + lane] = (_Float16)aval;   // o = lane
  }

  // ---- node weights (independent of agg; overlap barrier drain)
  const int o = w * 16 + r;
  Frag8 B1[2], B2[2];
#pragma unroll
  for (int ks = 0; ks < 2; ++ks) {
    const float* p1 = out1_w + o * 68 + 4 + ks * 32 + q * 8;
    const float4 c0 = *(const float4*)p1;
    const float4 c1 = *(const float4*)(p1 + 4);
    B1[ks].u[0] = pk16(c0.x, c0.y); B1[ks].u[1] = pk16(c0.z, c0.w);
    B1[ks].u[2] = pk16(c1.x, c1.y); B1[ks].u[3] = pk16(c1.z, c1.w);
    const float* p2 = out2_w + o * 64 + ks * 32 + q * 8;
    const float4 e0 = *(const float4*)p2;
    const float4 e1 = *(const float4*)(p2 + 4);
    B2[ks].u[0] = pk16(e0.x, e0.y); B2[ks].u[1] = pk16(e0.z, e0.w);
    B2[ks].u[2] = pk16(e1.x, e1.y); B2[ks].u[3] = pk16(e1.z, e1.w);
  }
  const float4 w1x = *(const float4*)(out1_w + o * 68);
  const float b1o = out1_b[o];
  const float b2o = out2_b[o];
  __syncthreads();   // AggL complete; Vh dead from here (H1L/H2L alias it)

  // ---------------- node phase (16 rows) ----------------
  // Layer 1: h1[n][o] = relu(b1 + x[n]·w1x + agg[n]·W1k[o])
  {
    Frag8 A0, A1;
    A0.f = *(const f16x8*)(AggL + r * 72 + q * 8);
    A1.f = *(const f16x8*)(AggL + r * 72 + 32 + q * 8);
    f32x4 d = {b1o, b1o, b1o, b1o};
    d = MFMA16(A0.f, B1[0].f, d);
    d = MFMA16(A1.f, B1[1].f, d);
#pragma unroll
    for (int reg = 0; reg < 4; ++reg) {
      const int n = q * 4 + reg;
      const float4 x = Xl[n];
      const float hv = d[reg] + x.x*w1x.x + x.y*w1x.y + x.z*w1x.z + x.w*w1x.w;
      H1L[n * 72 + o] = (_Float16)fmaxf(hv, 0.f);
    }
  }
  __syncthreads();

  // Layer 2: h2 = relu(b2 + h1·W2o^T)
  {
    Frag8 A0, A1;
    A0.f = *(const f16x8*)(H1L + r * 72 + q * 8);
    A1.f = *(const f16x8*)(H1L + r * 72 + 32 + q * 8);
    f32x4 d = {b2o, b2o, b2o, b2o};
    d = MFMA16(A0.f, B2[0].f, d);
    d = MFMA16(A1.f, B2[1].f, d);
#pragma unroll
    for (int reg = 0; reg < 4; ++reg) {
      const int n = q * 4 + reg;
      H2L[n * 72 + o] = (_Float16)fmaxf(d[reg], 0.f);
    }
  }
  __syncthreads();

  // Layer 3 (wave 0): delta[n][dm] = b3[dm] + h2[n]·W3[dm]; out = x + delta
  if (w == 0) {
    Frag8 B3[2];
#pragma unroll
    for (int ks = 0; ks < 2; ++ks) {
      const float* p3 = out3_w + (r & 3) * 64 + ks * 32 + q * 8;
      const float4 c0 = *(const float4*)p3;
      const float4 c1 = *(const float4*)(p3 + 4);
      B3[ks].u[0] = pk16(c0.x, c0.y); B3[ks].u[1] = pk16(c0.z, c0.w);
      B3[ks].u[2] = pk16(c1.x, c1.y); B3[ks].u[3] = pk16(c1.z, c1.w);
    }
    Frag8 A0, A1;
    A0.f = *(const f16x8*)(H2L + r * 72 + q * 8);
    A1.f = *(const f16x8*)(H2L + r * 72 + 32 + q * 8);
    const float b3o = out3_b[r & 3];
    f32x4 d = {b3o, b3o, b3o, b3o};
    d = MFMA16(A0.f, B3[0].f, d);
    d = MFMA16(A1.f, B3[1].f, d);
    if (r < 4) {  // valid cols; rows q*4+reg all valid
      const float* xf = (const float*)Xl;
#pragma unroll
      for (int reg = 0; reg < 4; ++reg) {
        const int n = q * 4 + reg;
        out[((b * NN + n_base + n) * NTO + t) * ND + r] = xf[n * 4 + r] + d[reg];
      }
    }
  }
}

extern "C" void kernel_launch(void* const* d_in, const int* in_sizes, int n_in,
                              void* d_out, int out_size, void* d_ws, size_t ws_size,
                              hipStream_t stream) {
  const float* inputs   = (const float*)d_in[0];
  const float* rel_type = (const float*)d_in[1];
  const float* fc1_w  = (const float*)d_in[4];
  const float* fc1_b  = (const float*)d_in[5];
  const float* fc2_w  = (const float*)d_in[6];
  const float* fc2_b  = (const float*)d_in[7];
  const float* out1_w = (const float*)d_in[8];
  const float* out1_b = (const float*)d_in[9];
  const float* out2_w = (const float*)d_in[10];
  const float* out2_b = (const float*)d_in[11];
  const float* out3_w = (const float*)d_in[12];
  const float* out3_b = (const float*)d_in[13];
  float* out = (float*)d_out;

  nri_fused_kernel<<<NB * NTO * 4, 256, 0, stream>>>(
      inputs, rel_type, fc1_w, fc1_b, fc2_w, fc2_b,
      out1_w, out1_b, out2_w, out2_b, out3_w, out3_b, out);
}